// Round 1
// baseline (348.367 us; speedup 1.0000x reference)
//
#include <hip/hip_runtime.h>

using half8   = __attribute__((ext_vector_type(8))) _Float16;
using floatx4 = __attribute__((ext_vector_type(4))) float;

// Repack quant_weights [co][c][kh][kw] fp32{-1,0,1} -> wre[(kh*3+kw)][co][c] f16
__global__ void repack_weights(const float* __restrict__ qw,
                               _Float16* __restrict__ wre, int n) {
  int t = blockIdx.x * 256 + threadIdx.x;
  if (t >= n) return;
  int c  = t & 255;
  int co = (t >> 8) & 255;
  int s  = t >> 16;                      // 0..8 = kh*3+kw
  wre[t] = (_Float16)qw[(co * 256 + c) * 9 + s];
}

// Implicit-GEMM binary conv: out[b,co,h,w] = scale[co]*sum sign*x + bias[co]
// Block tile: 128 cout x 112 pixels (2 rows x 56), K-chunks of 32 input channels.
// LDS x-tile layout: xs[row 0..3][col 0..57][c 0..31] f16 (c innermost -> ds_read_b128)
__global__ __launch_bounds__(256, 2) void binconv_mfma(
    const float* __restrict__ x,
    const float* __restrict__ scale,
    const float* __restrict__ bias,
    const _Float16* __restrict__ wre,
    float* __restrict__ out)
{
  __shared__ _Float16 xs[4 * 58 * 32];   // 14,848 B

  const int tid  = threadIdx.x;
  const int nb   = blockIdx.x;           // 0..895 : (b, h-pair)
  const int mb   = blockIdx.y;           // 0..1   : cout half
  const int b    = nb / 28;
  const int h0   = (nb % 28) * 2;
  const int wave = tid >> 6;
  const int lane = tid & 63;
  const int nl   = lane & 15;            // MFMA: n (B) / m (A) index
  const int quad = lane >> 4;            // MFMA: k-group
  const int co_wave = mb * 128 + wave * 32;

  // zero halo columns (col 0 and 57) once; never overwritten afterwards
  {
    int c = tid & 31;
    int g = tid >> 5;                    // 0..7
    int r = g >> 1;
    int side = g & 1;
    xs[(r * 58 + side * 57) * 32 + c] = (_Float16)0.0f;
  }

  // per-lane B-fragment base byte offsets within xs for j = 0..6
  int bbase[7];
#pragma unroll
  for (int j = 0; j < 7; ++j) {
    int n = j * 16 + nl;                 // 0..111 pixel within tile
    int r = (n >= 56) ? 1 : 0;
    int w = n - r * 56;
    bbase[j] = (r * 58 + w) * 64 + quad * 16;   // bytes; (+ (kh*58+kw)*64 per shift)
  }

  // per-lane A-fragment pointers (one per 16-row m-tile)
  const _Float16* aptr0 = wre + (co_wave + nl) * 256 + quad * 8;
  const _Float16* aptr1 = wre + (co_wave + 16 + nl) * 256 + quad * 8;

  floatx4 acc[2][7];
#pragma unroll
  for (int mi = 0; mi < 2; ++mi)
#pragma unroll
    for (int j = 0; j < 7; ++j)
      acc[mi][j] = (floatx4){0.f, 0.f, 0.f, 0.f};

  const int sc = tid & 31;               // staging: channel within chunk
  const int sg = tid >> 5;               // staging: work-group 0..7

  for (int c0 = 0; c0 < 256; c0 += 32) {
    // ---- stage x chunk into LDS: 32c x 4 rows x 56 cols (+pad), fp32->f16 ----
    for (int p = sg; p < 28; p += 8) {   // p = r*7 + wg
      int r  = p / 7;
      int wg = p - r * 7;
      int h  = h0 - 1 + r;
      int w0 = wg * 8;
      float v[8];
      if (h >= 0 && h < 56) {
        const float* src = x + (((long)b * 256 + c0 + sc) * 56 + h) * 56 + w0;
        float4 u0 = *reinterpret_cast<const float4*>(src);
        float4 u1 = *reinterpret_cast<const float4*>(src + 4);
        v[0] = u0.x; v[1] = u0.y; v[2] = u0.z; v[3] = u0.w;
        v[4] = u1.x; v[5] = u1.y; v[6] = u1.z; v[7] = u1.w;
      } else {
#pragma unroll
        for (int i = 0; i < 8; ++i) v[i] = 0.f;
      }
      int basei = (r * 58 + 1 + w0) * 32 + sc;
#pragma unroll
      for (int i = 0; i < 8; ++i) xs[basei + i * 32] = (_Float16)v[i];
    }
    __syncthreads();

    // ---- compute: 9 shifts x (2m x 7n) MFMA 16x16x32 f16, K = this c-chunk ----
#pragma unroll
    for (int s = 0; s < 9; ++s) {
      const int kh = s / 3, kw = s - kh * 3;
      half8 a0 = *reinterpret_cast<const half8*>(aptr0 + s * 65536 + c0);
      half8 a1 = *reinterpret_cast<const half8*>(aptr1 + s * 65536 + c0);
      const int soff = (kh * 58 + kw) * 64;
#pragma unroll
      for (int j = 0; j < 7; ++j) {
        half8 bf = *reinterpret_cast<const half8*>(
            reinterpret_cast<const char*>(xs) + bbase[j] + soff);
        acc[0][j] = __builtin_amdgcn_mfma_f32_16x16x32_f16(a0, bf, acc[0][j], 0, 0, 0);
        acc[1][j] = __builtin_amdgcn_mfma_f32_16x16x32_f16(a1, bf, acc[1][j], 0, 0, 0);
      }
    }
    __syncthreads();
  }

  // ---- epilogue: scale + bias, fp32 stores ----
  // C/D layout: n = lane&15 (col), m = quad*4 + reg (row)
#pragma unroll
  for (int mi = 0; mi < 2; ++mi) {
#pragma unroll
    for (int reg = 0; reg < 4; ++reg) {
      int co = co_wave + mi * 16 + quad * 4 + reg;
      float s_ = scale[co];
      float bi = bias[co];
#pragma unroll
      for (int j = 0; j < 7; ++j) {
        int n = j * 16 + nl;
        int r = (n >= 56) ? 1 : 0;
        int w = n - r * 56;
        out[(((long)b * 256 + co) * 56 + (h0 + r)) * 56 + w] =
            acc[mi][j][reg] * s_ + bi;
      }
    }
  }
}

extern "C" void kernel_launch(void* const* d_in, const int* in_sizes, int n_in,
                              void* d_out, int out_size, void* d_ws, size_t ws_size,
                              hipStream_t stream) {
  const float* x     = (const float*)d_in[0];   // [32,256,56,56]
  const float* scale = (const float*)d_in[1];   // [256]
  const float* qw    = (const float*)d_in[2];   // [256,256,3,3] in {-1,0,1}
  const float* bias  = (const float*)d_in[3];   // [256]
  float* out = (float*)d_out;                   // [32,256,56,56] fp32

  _Float16* wre = (_Float16*)d_ws;              // 9*256*256 f16 = 1.13 MB scratch

  const int nw = 9 * 256 * 256;
  repack_weights<<<(nw + 255) / 256, 256, 0, stream>>>(qw, wre, nw);

  dim3 grid(896, 2);                            // 896 (b,h-pair) x 2 cout-halves
  binconv_mfma<<<grid, 256, 0, stream>>>(x, scale, bias, wre, out);
}